// Round 8
// baseline (577.114 us; speedup 1.0000x reference)
//
#include <hip/hip_runtime.h>
#include <hip/hip_bf16.h>

// NewellGRUModel: B=512, S=1024, F=16, H=64.  bf16 in/out (proven r2..r17).
//
// r18 (recompile of r18 theory; r18a fixes cvt_pkrtz return-type mismatch):
// r17 post-mortem -- readlane broadcast was hazard-serialized net-minus;
// r13's xpv top-of-step read was ALREADY hiding the hr latency (same in-order
// DS queue). The real hole: the wave has no independent VALU work inside the
// h write->read window (~140cyc) + trans tail (~60). Fix: single wave does
// its OWN x-proj as 24 f16-dot2 (exact products for bf16 inputs), with
// x-weights packed f16 in LDS and RELOADED EVERY STEP (24 short-lived dwords,
// not 45 persistent -> no r15 register explosion; a volatile s_mov launders
// the address so the loads can't be hoisted into loop-invariant parked regs).
// Schedule: [unpack/pack x | xproj 24dot2 | reload xw | h-dots 96dot2
// gate-major w/ early sigmoid | gates | raw-x prefetch | h write | hr reads].
// DS queue [xw,raw,write,hr]: next iter's xproj (~120cyc indep VALU) sits
// exactly in the h round-trip window -> ~20cyc exposed. No producer, no
// barriers. h-dot chains bit-identical to r13.

#define KEEP(x) asm volatile("" : "+v"(x))

typedef _Float16 f16x2 __attribute__((ext_vector_type(2)));
union H2U { unsigned int u; f16x2 h; };
union FU  { unsigned int u; float f; };

#if defined(__has_builtin)
#  if __has_builtin(__builtin_amdgcn_fdot2)
#    define HAS_FDOT2 1
#  endif
#endif
#ifndef HAS_FDOT2
#  define HAS_FDOT2 0
#endif

// acc += a2[0]*b2[0] + a2[1]*b2[1]  (fp32 accumulate)
static __device__ __forceinline__ float dot2acc(unsigned int araw, unsigned int braw, float acc) {
    H2U a, b; a.u = araw; b.u = braw;
#if HAS_FDOT2
    return __builtin_amdgcn_fdot2(a.h, b.h, acc, false);
#else
    return fmaf((float)a.h.x, (float)b.h.x, fmaf((float)a.h.y, (float)b.h.y, acc));
#endif
}

// pack two f32 (exact bf16-derived values) into f16x2 dword (RTZ; exact here)
static __device__ __forceinline__ unsigned int pk16(float lo, float hi) {
    auto v = __builtin_amdgcn_cvt_pkrtz(lo, hi);   // __fp16 ext_vector(2)
    union { decltype(v) h; unsigned int u; } u;
    u.h = v;
    return u.u;
}

template<bool BF16>
struct IO {
    static __device__ __forceinline__ float ld(const void* p, int i) {
        if constexpr (BF16) {
            unsigned short u = ((const unsigned short*)p)[i];
            FU c; c.u = (unsigned int)u << 16;
            return c.f;
        } else {
            return ((const float*)p)[i];
        }
    }
    static __device__ __forceinline__ void st(void* p, int i, float v) {
        if constexpr (BF16) ((__hip_bfloat16*)p)[i] = __float2bfloat16(v);
        else ((float*)p)[i] = v;
    }
};

// mode: 0 = buffers are bf16, 1 = buffers are fp32.
__global__ void detect_dtype_kernel(const void* rkbuf, int* flag) {
    const float* f = (const float*)rkbuf;
    int ok = 0;
    for (int i = 0; i < 64; ++i) {
        float a = fabsf(f[i]);
        ok += (a > 1e-5f && a < 2.0f) ? 1 : 0;
    }
    *flag = (ok >= 48) ? 1 : 0;
}

template<bool BF16>
__global__ __launch_bounds__(64, 1)
void gru_sx_kernel(const void* __restrict__ inp, const void* __restrict__ gk,
                   const void* __restrict__ rk,  const void* __restrict__ gb,
                   const void* __restrict__ w1,  const void* __restrict__ b1v,
                   const void* __restrict__ gam, const void* __restrict__ bet,
                   const void* __restrict__ muv, const void* __restrict__ vav,
                   const void* __restrict__ w2,  const void* __restrict__ bb2,
                   const void* __restrict__ Tp,  const int* __restrict__ mode,
                   void* __restrict__ out)
{
    const int want = BF16 ? 0 : 1;
    if (*mode != want) return;   // uniform branch, whole block exits

    const int b = blockIdx.x;
    const int l = threadIdx.x;   // 0..63, lane = output unit

    // Raw x: BF16 -> whole batch (32 KB); FP32 -> half batch, restaged once.
    __shared__ __align__(16) unsigned char xsm[32768];
    __shared__ __align__(16) uint4 xws4[6*64];      // packed-f16 x-weights, 6 KB
    __shared__ __align__(16) _Float16 hsf[64];
    __shared__ __align__(16) float sredf[64];

    using io = IO<BF16>;
    const uint4* gin = (const uint4*)inp;
    uint4* xvw = (uint4*)xsm;

    // ---- stage raw x (single wave: DS in-order, no barrier ever) ----
    if constexpr (BF16) {
#pragma unroll 4
        for (int i = 0; i < 32; ++i)
            xvw[i*64 + l] = gin[b*2048 + i*64 + l];     // whole batch, raw bf16
    } else {
#pragma unroll 4
        for (int i = 0; i < 32; ++i)
            xvw[i*64 + l] = gin[b*4096 + i*64 + l];     // first half, raw f32
    }

    // ---- stage x-proj weights packed f16 pairs: xws4[(g*2+q)*64+l] ----
#pragma unroll 1
    for (int g = 0; g < 3; ++g) {
#pragma unroll
        for (int q = 0; q < 2; ++q) {
            unsigned int d[4];
#pragma unroll
            for (int j = 0; j < 4; ++j) {
                const int pj = q*4 + j;            // pair: channels 2pj, 2pj+1
                const int c0 = 2*pj, c1 = 2*pj + 1;
                const float f0 = (c0 < 15) ? io::ld(gk, c0*192 + g*64 + l) : 0.0f;
                const float f1 = (c1 < 15) ? io::ld(gk, c1*192 + g*64 + l) : 0.0f;
                d[j] = pk16(f0, f1);               // exact for bf16-derived
            }
            xws4[(g*2 + q)*64 + l] = make_uint4(d[0], d[1], d[2], d[3]);
        }
    }

    // ---- recurrent weights packed f16x2 (96 dwords; bf16->f16 exact) ----
    unsigned int wzp[32], wrp[32], whp[32];
#pragma unroll
    for (int p = 0; p < 32; ++p) {
        H2U z, r, hh;
        z.h  = f16x2{(_Float16)io::ld(rk, (2*p)*192 + l),
                     (_Float16)io::ld(rk, (2*p+1)*192 + l)};
        r.h  = f16x2{(_Float16)io::ld(rk, (2*p)*192 + 64 + l),
                     (_Float16)io::ld(rk, (2*p+1)*192 + 64 + l)};
        hh.h = f16x2{(_Float16)io::ld(rk, (2*p)*192 + 128 + l),
                     (_Float16)io::ld(rk, (2*p+1)*192 + 128 + l)};
        wzp[p] = z.u; wrp[p] = r.u; whp[p] = hh.u;
        KEEP(wzp[p]); KEEP(wrp[p]); KEEP(whp[p]);
    }
    const float bz  = io::ld(gb, l)      + io::ld(gb, 192 + l);
    const float br  = io::ld(gb, 64 + l) + io::ld(gb, 192 + 64 + l);
    const float bax = io::ld(gb, 128 + l);
    const float bah = io::ld(gb, 192 + 128 + l);   // b_r[h]

    // ---- delta-channel partial sum over staged portion ----
    float dsum = 0.0f;
    if constexpr (BF16) {
        const unsigned short* xs16 = (const unsigned short*)xsm;
#pragma unroll
        for (int k = 0; k < 16; ++k) {
            FU c; c.u = (unsigned int)xs16[(l + 64*k)*16 + 15] << 16;
            dsum += c.f;
        }
    } else {
        const float* xsf = (const float*)xsm;
#pragma unroll
        for (int k = 0; k < 8; ++k)
            dsum += xsf[(l + 64*k)*16 + 15];
    }

    const uint4* hp  = (const uint4*)hsf;          // uniform -> broadcast
    const uint4* xvr = (const uint4*)xsm;

    // carried raw-x regs (bf16: 8 dwords; fp32: 16 floats)
    uint4  cr16[2] = {}, pr16[2] = {};
    float4 cr32[4] = {}, pr32[4] = {};
    if constexpr (BF16) { cr16[0] = xvr[0]; cr16[1] = xvr[1]; }
    else { const float4* lp = (const float4*)xsm;
           cr32[0]=lp[0]; cr32[1]=lp[1]; cr32[2]=lp[2]; cr32[3]=lp[3]; }

    // carried x-weight dwords (reloaded every step; laundered address)
    uint4 xwq0, xwq1, xwq2, xwq3, xwq4, xwq5;
    {
        const uint4* xq = xws4 + l;
        xwq0 = xq[0];   xwq1 = xq[64];  xwq2 = xq[128];
        xwq3 = xq[192]; xwq4 = xq[256]; xwq5 = xq[320];
    }

    uint4 hr[8];
#pragma unroll
    for (int i = 0; i < 8; ++i) hr[i] = make_uint4(0, 0, 0, 0);
    float h = 0.0f;

    // ---- main loop: zero barriers, single wave ----
#pragma unroll 1
    for (int s = 0; s < 1024; ++s) {
        if constexpr (!BF16) {
            if (s == 511) {   // restage second half before prefetching x(512)
#pragma unroll 4
                for (int i = 0; i < 32; ++i)
                    xvw[i*64 + l] = gin[b*4096 + 2048 + i*64 + l];
                const float* xsf = (const float*)xsm;
#pragma unroll
                for (int k = 0; k < 8; ++k)
                    dsum += xsf[(l + 64*k)*16 + 15];
            }
        }

        // ---- unpack current x -> packed f16 pairs (exact) ----
        unsigned int xcp[8];
        if constexpr (BF16) {
            const unsigned int dw[8] = {cr16[0].x, cr16[0].y, cr16[0].z, cr16[0].w,
                                        cr16[1].x, cr16[1].y, cr16[1].z, cr16[1].w};
#pragma unroll
            for (int j = 0; j < 8; ++j) {
                FU lo, hi; lo.u = dw[j] << 16; hi.u = dw[j] & 0xffff0000u;
                xcp[j] = pk16(lo.f, hi.f);
            }
        } else {
            const float xf[16] = {cr32[0].x,cr32[0].y,cr32[0].z,cr32[0].w,
                                  cr32[1].x,cr32[1].y,cr32[1].z,cr32[1].w,
                                  cr32[2].x,cr32[2].y,cr32[2].z,cr32[2].w,
                                  cr32[3].x,cr32[3].y,cr32[3].z,cr32[3].w};
#pragma unroll
            for (int j = 0; j < 8; ++j) xcp[j] = pk16(xf[2*j], xf[2*j+1]);
        }

        // ---- x-proj: 24 dot2 (independent of h -> fills hr window) ----
        float az = bz, arr = br, ax = bax;
        {
            const unsigned int wzx[8] = {xwq0.x,xwq0.y,xwq0.z,xwq0.w, xwq1.x,xwq1.y,xwq1.z,xwq1.w};
            const unsigned int wrx[8] = {xwq2.x,xwq2.y,xwq2.z,xwq2.w, xwq3.x,xwq3.y,xwq3.z,xwq3.w};
            const unsigned int whx[8] = {xwq4.x,xwq4.y,xwq4.z,xwq4.w, xwq5.x,xwq5.y,xwq5.z,xwq5.w};
#pragma unroll
            for (int j = 0; j < 8; ++j) az  = dot2acc(xcp[j], wzx[j], az);
#pragma unroll
            for (int j = 0; j < 8; ++j) arr = dot2acc(xcp[j], wrx[j], arr);
#pragma unroll
            for (int j = 0; j < 8; ++j) ax  = dot2acc(xcp[j], whx[j], ax);
        }

        // ---- reload x-weights for next iter (laundered: no hoisting) ----
        {
            unsigned int zz;
            asm volatile("s_mov_b32 %0, 0" : "=s"(zz));
            const uint4* xq = xws4 + l + zz;
            xwq0 = xq[0];   xwq1 = xq[64];  xwq2 = xq[128];
            xwq3 = xq[192]; xwq4 = xq[256]; xwq5 = xq[320];
        }

        // ---- h-dots, gate-major (per-acc chain order identical to r13) ----
        float az1 = 0.0f;
#pragma unroll
        for (int i = 0; i < 4; ++i) {
            const uint4 d = hr[i];
            az  = dot2acc(d.x, wzp[4*i+0], az);
            az  = dot2acc(d.y, wzp[4*i+1], az);
            az  = dot2acc(d.z, wzp[4*i+2], az);
            az  = dot2acc(d.w, wzp[4*i+3], az);
        }
#pragma unroll
        for (int i = 4; i < 8; ++i) {
            const uint4 d = hr[i];
            az1 = dot2acc(d.x, wzp[4*i+0], az1);
            az1 = dot2acc(d.y, wzp[4*i+1], az1);
            az1 = dot2acc(d.z, wzp[4*i+2], az1);
            az1 = dot2acc(d.w, wzp[4*i+3], az1);
        }
        az += az1;
        const float z = __builtin_amdgcn_rcpf(1.0f + __expf(-az));   // early

        float ar1 = 0.0f;
#pragma unroll
        for (int i = 0; i < 4; ++i) {
            const uint4 d = hr[i];
            arr = dot2acc(d.x, wrp[4*i+0], arr);
            arr = dot2acc(d.y, wrp[4*i+1], arr);
            arr = dot2acc(d.z, wrp[4*i+2], arr);
            arr = dot2acc(d.w, wrp[4*i+3], arr);
        }
#pragma unroll
        for (int i = 4; i < 8; ++i) {
            const uint4 d = hr[i];
            ar1 = dot2acc(d.x, wrp[4*i+0], ar1);
            ar1 = dot2acc(d.y, wrp[4*i+1], ar1);
            ar1 = dot2acc(d.z, wrp[4*i+2], ar1);
            ar1 = dot2acc(d.w, wrp[4*i+3], ar1);
        }
        arr += ar1;
        const float r = __builtin_amdgcn_rcpf(1.0f + __expf(-arr));  // early

        float ah = bah, ah1 = 0.0f;
#pragma unroll
        for (int i = 0; i < 4; ++i) {
            const uint4 d = hr[i];
            ah  = dot2acc(d.x, whp[4*i+0], ah);
            ah  = dot2acc(d.y, whp[4*i+1], ah);
            ah  = dot2acc(d.z, whp[4*i+2], ah);
            ah  = dot2acc(d.w, whp[4*i+3], ah);
        }
#pragma unroll
        for (int i = 4; i < 8; ++i) {
            const uint4 d = hr[i];
            ah1 = dot2acc(d.x, whp[4*i+0], ah1);
            ah1 = dot2acc(d.y, whp[4*i+1], ah1);
            ah1 = dot2acc(d.z, whp[4*i+2], ah1);
            ah1 = dot2acc(d.w, whp[4*i+3], ah1);
        }
        ah += ah1;

        const float pre = fmaf(r, ah, ax);
        const float e2  = __expf(2.0f * pre);
        const float th  = 1.0f - 2.0f * __builtin_amdgcn_rcpf(e2 + 1.0f);
        h = fmaf(z, h - th, th);     // z*h + (1-z)*tanh

        // ---- raw x prefetch for s+1 (issued BEFORE h write: returns first) --
        if (s < 1023) {
            if constexpr (BF16) {
                pr16[0] = xvr[(s+1)*2]; pr16[1] = xvr[(s+1)*2 + 1];
            } else {
                const float4* lp = (const float4*)xsm;
                const int ix = ((s+1) & 511) * 4;
                pr32[0]=lp[ix]; pr32[1]=lp[ix+1]; pr32[2]=lp[ix+2]; pr32[3]=lp[ix+3];
            }
        }

        // ---- h write + broadcast reads (consumed next iter after xproj) ----
        hsf[l] = (_Float16)h;        // same-wave DS: in-order
#pragma unroll
        for (int i = 0; i < 8; ++i) hr[i] = hp[i];

        if constexpr (BF16) { cr16[0] = pr16[0]; cr16[1] = pr16[1]; }
        else { cr32[0]=pr32[0]; cr32[1]=pr32[1]; cr32[2]=pr32[2]; cr32[3]=pr32[3]; }
    }

    // ---- epilogue: delta effect + dense head (single wave) ----
#pragma unroll
    for (int off = 1; off < 64; off <<= 1)
        dsum += __shfl_xor(dsum, off, 64);           // all lanes hold total
    const float T0 = io::ld(Tp, 0);
    const float state = fmaf(T0 * (1.0f / 1024.0f), dsum, h);
    sredf[l] = state;                                // same-wave DS, in-order

    const int j = l;   // 0..63
    float acc = io::ld(b1v, j);
#pragma unroll
    for (int k = 0; k < 64; ++k)
        acc = fmaf(sredf[k], io::ld(w1, k*64 + j), acc);
    acc = fmaxf(acc, 0.0f);                                  // ReLU
    const float inv = rsqrtf(io::ld(vav, j) + 0.001f);       // BN_EPS
    acc = fmaf((acc - io::ld(muv, j)) * inv, io::ld(gam, j), io::ld(bet, j));

    float v = acc * io::ld(w2, j);
#pragma unroll
    for (int off = 32; off > 0; off >>= 1)
        v += __shfl_down(v, off);
    if (j == 0) io::st(out, b, v + io::ld(bb2, 0));
}

extern "C" void kernel_launch(void* const* d_in, const int* in_sizes, int n_in,
                              void* d_out, int out_size, void* d_ws, size_t ws_size,
                              hipStream_t stream)
{
    const void* inp = d_in[0];   // (512,1024,16)
    const void* gk  = d_in[1];   // (15,192)
    const void* rk  = d_in[2];   // (64,192)
    const void* gb  = d_in[3];   // (2,192)
    const void* w1  = d_in[4];   // (64,64)
    const void* b1v = d_in[5];   // (64,)
    const void* gam = d_in[6];
    const void* bet = d_in[7];
    const void* muv = d_in[8];
    const void* vav = d_in[9];
    const void* w2  = d_in[10];  // (64,1)
    const void* bb2 = d_in[11];  // (1,)
    const void* Tp  = d_in[12];  // (1,)

    int* flag = (int*)d_ws;
    detect_dtype_kernel<<<dim3(1), dim3(1), 0, stream>>>(rk, flag);
    gru_sx_kernel<true ><<<dim3(512), dim3(64), 0, stream>>>(
        inp, gk, rk, gb, w1, b1v, gam, bet, muv, vav, w2, bb2, Tp, flag, d_out);
    gru_sx_kernel<false><<<dim3(512), dim3(64), 0, stream>>>(
        inp, gk, rk, gb, w1, b1v, gam, bet, muv, vav, w2, bb2, Tp, flag, d_out);
}